// Round 8
// baseline (465.849 us; speedup 1.0000x reference)
//
#include <hip/hip_runtime.h>

typedef unsigned short u16;
typedef unsigned int u32;
typedef __attribute__((ext_vector_type(8))) short short8;
typedef __attribute__((ext_vector_type(4))) float floatx4;

__device__ __forceinline__ float b2f(u16 v) {
  union { u32 u; float f; } x; x.u = ((u32)v) << 16; return x.f;
}
__device__ __forceinline__ u16 f2bf(float f) {
  union { float f; u32 u; } x; x.f = f;
  u32 r = (x.u + 0x7fffu + ((x.u >> 16) & 1u)) >> 16;  // RNE
  return (u16)r;
}

// C(bf16) = A @ W^T + bias ; A:[4096,1024] row-major (f32 or bf16 per template),
// W:[1024,1024] f32 row-major ([out,in]), bias f32.
// 128x128 tile, BK=64, 4 waves 2x2, each wave 64x64 via 4x4 of 16x16x32 bf16 MFMA.
template <int A_IS_F32>
__global__ __launch_bounds__(256, 2)
void gemm_nt_bias(const void* __restrict__ A0, const float* __restrict__ W0, const float* __restrict__ B0, u16* __restrict__ C0,
                  const void* __restrict__ A1, const float* __restrict__ W1, const float* __restrict__ B1, u16* __restrict__ C1,
                  const void* __restrict__ A2, const float* __restrict__ W2, const float* __restrict__ B2, u16* __restrict__ C2)
{
  constexpr int K = 1024, N = 1024;
  __shared__ __attribute__((aligned(16))) u16 As[128 * 64];
  __shared__ __attribute__((aligned(16))) u16 Bs[128 * 64];

  const int z = blockIdx.z;
  const void*  A  = z == 0 ? A0 : (z == 1 ? A1 : A2);
  const float* W  = z == 0 ? W0 : (z == 1 ? W1 : W2);
  const float* Bi = z == 0 ? B0 : (z == 1 ? B1 : B2);
  u16*         C  = z == 0 ? C0 : (z == 1 ? C1 : C2);

  const int tid  = threadIdx.x;
  const int lane = tid & 63;
  const int wave = tid >> 6;
  const int l16  = lane & 15;
  const int quad = lane >> 4;
  const int wm = wave >> 1, wn = wave & 1;
  const int m0 = blockIdx.x * 128;
  const int n0 = blockIdx.y * 128;

  floatx4 acc[4][4];
#pragma unroll
  for (int i = 0; i < 4; ++i)
#pragma unroll
    for (int j = 0; j < 4; ++j)
#pragma unroll
      for (int e = 0; e < 4; ++e) acc[i][j][e] = 0.f;

  for (int k0 = 0; k0 < K; k0 += 64) {
#pragma unroll
    for (int i = 0; i < 4; ++i) {
      const int f = i * 256 + tid;
      const int r = f >> 3;            // row 0..127
      const int c = (f & 7) * 8;       // k-offset 0..56
      u16 ta[8];
      if (A_IS_F32) {
        const float* pa = (const float*)A + (size_t)(m0 + r) * K + k0 + c;
        float4 a0 = *(const float4*)pa, a1 = *(const float4*)(pa + 4);
        ta[0] = f2bf(a0.x); ta[1] = f2bf(a0.y); ta[2] = f2bf(a0.z); ta[3] = f2bf(a0.w);
        ta[4] = f2bf(a1.x); ta[5] = f2bf(a1.y); ta[6] = f2bf(a1.z); ta[7] = f2bf(a1.w);
      } else {
        const u16* pa = (const u16*)A + (size_t)(m0 + r) * K + k0 + c;
        *(uint4*)ta = *(const uint4*)pa;
      }
      *(uint4*)&As[r * 64 + c] = *(const uint4*)ta;
      const float* pw = W + (size_t)(n0 + r) * K + k0 + c;
      float4 w0 = *(const float4*)pw, w1 = *(const float4*)(pw + 4);
      u16 tw[8];
      tw[0] = f2bf(w0.x); tw[1] = f2bf(w0.y); tw[2] = f2bf(w0.z); tw[3] = f2bf(w0.w);
      tw[4] = f2bf(w1.x); tw[5] = f2bf(w1.y); tw[6] = f2bf(w1.z); tw[7] = f2bf(w1.w);
      *(uint4*)&Bs[r * 64 + c] = *(const uint4*)tw;
    }
    __syncthreads();
#pragma unroll
    for (int ks = 0; ks < 2; ++ks) {
      short8 af[4], bf[4];
#pragma unroll
      for (int mt = 0; mt < 4; ++mt)
        af[mt] = *(const short8*)&As[(wm * 64 + mt * 16 + l16) * 64 + ks * 32 + quad * 8];
#pragma unroll
      for (int nt = 0; nt < 4; ++nt)
        bf[nt] = *(const short8*)&Bs[(wn * 64 + nt * 16 + l16) * 64 + ks * 32 + quad * 8];
#pragma unroll
      for (int mt = 0; mt < 4; ++mt)
#pragma unroll
        for (int nt = 0; nt < 4; ++nt)
          acc[mt][nt] = __builtin_amdgcn_mfma_f32_16x16x32_bf16(af[mt], bf[nt], acc[mt][nt], 0, 0, 0);
    }
    __syncthreads();
  }

  float bb[4];
#pragma unroll
  for (int nt = 0; nt < 4; ++nt) bb[nt] = Bi[n0 + wn * 64 + nt * 16 + l16];
#pragma unroll
  for (int mt = 0; mt < 4; ++mt) {
#pragma unroll
    for (int r = 0; r < 4; ++r) {
      const int row = m0 + wm * 64 + mt * 16 + quad * 4 + r;
      u16* crow = C + (size_t)row * N + n0 + wn * 64 + l16;
#pragma unroll
      for (int nt = 0; nt < 4; ++nt)
        crow[nt * 16] = f2bf(acc[mt][nt][r] + bb[nt]);
    }
  }
}

// Flash attention, Br=Bc=64, Hd=64, heads packed as cols h*64..h*64+63 of [B*S,1024].
// All bf16 in ws. O = softmax(Q K^T / 8) V.  Swap (Q,K) for the K->Q branch (V shared).
__global__ __launch_bounds__(256, 2)
void flash64(const u16* __restrict__ Qw, const u16* __restrict__ Kw,
             const u16* __restrict__ Vw, u16* __restrict__ Ow)
{
  __shared__ __attribute__((aligned(16))) u16 qs[64 * 64];
  __shared__ __attribute__((aligned(16))) u16 ks[64 * 64];
  __shared__ __attribute__((aligned(16))) u16 vT[64 * 64];  // vT[d][s]
  __shared__ __attribute__((aligned(16))) u16 ps[64 * 64];

  const int tid  = threadIdx.x;
  const int lane = tid & 63;
  const int wave = tid >> 6;
  const int l16  = lane & 15;
  const int quad = lane >> 4;
  const int bh = blockIdx.y;
  const int b = bh >> 4, h = bh & 15;
  const int q0 = blockIdx.x * 64;
  const size_t colBase = (size_t)h * 64;
  const size_t qbase = ((size_t)(b * 1024 + q0)) * 1024 + colBase;

  for (int i = tid; i < 512; i += 256) {
    const int r = i >> 3, c = (i & 7) * 8;
    *(uint4*)&qs[r * 64 + c] = *(const uint4*)&Qw[qbase + (size_t)r * 1024 + c];
  }
  __syncthreads();
  short8 aq[2];
#pragma unroll
  for (int k2 = 0; k2 < 2; ++k2)
    aq[k2] = *(const short8*)&qs[(wave * 16 + l16) * 64 + k2 * 32 + quad * 8];

  floatx4 accO[4];
#pragma unroll
  for (int nt = 0; nt < 4; ++nt)
#pragma unroll
    for (int e = 0; e < 4; ++e) accO[nt][e] = 0.f;
  float mrow[4], lrow[4];
#pragma unroll
  for (int r = 0; r < 4; ++r) { mrow[r] = -1e30f; lrow[r] = 0.f; }

  for (int jt = 0; jt < 16; ++jt) {
    __syncthreads();
    const size_t kb = ((size_t)(b * 1024 + jt * 64)) * 1024 + colBase;
    for (int i = tid; i < 512; i += 256) {
      const int r = i >> 3, c = (i & 7) * 8;
      *(uint4*)&ks[r * 64 + c] = *(const uint4*)&Kw[kb + (size_t)r * 1024 + c];
      uint4 vv = *(const uint4*)&Vw[kb + (size_t)r * 1024 + c];
      const u16* pv = (const u16*)&vv;
#pragma unroll
      for (int e = 0; e < 8; ++e) vT[(c + e) * 64 + r] = pv[e];
    }
    __syncthreads();

    floatx4 sacc[4];
#pragma unroll
    for (int nt = 0; nt < 4; ++nt)
#pragma unroll
      for (int e = 0; e < 4; ++e) sacc[nt][e] = 0.f;
#pragma unroll
    for (int k2 = 0; k2 < 2; ++k2) {
#pragma unroll
      for (int nt = 0; nt < 4; ++nt) {
        short8 bf = *(const short8*)&ks[(nt * 16 + l16) * 64 + k2 * 32 + quad * 8];
        sacc[nt] = __builtin_amdgcn_mfma_f32_16x16x32_bf16(aq[k2], bf, sacc[nt], 0, 0, 0);
      }
    }

    const float scale = 0.125f;  // 1/sqrt(64)
    float mnew[4], alpha[4];
#pragma unroll
    for (int r = 0; r < 4; ++r) {
      float mx = fmaxf(fmaxf(sacc[0][r], sacc[1][r]), fmaxf(sacc[2][r], sacc[3][r])) * scale;
#pragma unroll
      for (int sh = 1; sh < 16; sh <<= 1) mx = fmaxf(mx, __shfl_xor(mx, sh, 64));
      mnew[r] = fmaxf(mrow[r], mx);
      alpha[r] = __expf(mrow[r] - mnew[r]);
      mrow[r] = mnew[r];
    }
#pragma unroll
    for (int nt = 0; nt < 4; ++nt) {
#pragma unroll
      for (int r = 0; r < 4; ++r) {
        float p = __expf(sacc[nt][r] * scale - mnew[r]);
        sacc[nt][r] = p;
        ps[(wave * 16 + quad * 4 + r) * 64 + nt * 16 + l16] = f2bf(p);
      }
    }
#pragma unroll
    for (int r = 0; r < 4; ++r) {
      float s = sacc[0][r] + sacc[1][r] + sacc[2][r] + sacc[3][r];
#pragma unroll
      for (int sh = 1; sh < 16; sh <<= 1) s += __shfl_xor(s, sh, 64);
      lrow[r] = lrow[r] * alpha[r] + s;
#pragma unroll
      for (int nt = 0; nt < 4; ++nt) accO[nt][r] *= alpha[r];
    }
    __syncthreads();
#pragma unroll
    for (int k2 = 0; k2 < 2; ++k2) {
      short8 ap = *(const short8*)&ps[(wave * 16 + l16) * 64 + k2 * 32 + quad * 8];
#pragma unroll
      for (int nt = 0; nt < 4; ++nt) {
        short8 bv = *(const short8*)&vT[(nt * 16 + l16) * 64 + k2 * 32 + quad * 8];
        accO[nt] = __builtin_amdgcn_mfma_f32_16x16x32_bf16(ap, bv, accO[nt], 0, 0, 0);
      }
    }
  }

  const size_t obase = ((size_t)(b * 1024 + q0 + wave * 16 + quad * 4)) * 1024 + colBase;
#pragma unroll
  for (int nt = 0; nt < 4; ++nt)
#pragma unroll
    for (int r = 0; r < 4; ++r)
      Ow[obase + (size_t)r * 1024 + nt * 16 + l16] = f2bf(accO[nt][r] / lrow[r]);
}

// out(F32!) = LN(residual_f32 + X_bf16) * gamma_f32 + beta_f32 ; one block per row of 1024
__global__ __launch_bounds__(256)
void ln_residual(const u16* __restrict__ TQ, const u16* __restrict__ TK,
                 const float* __restrict__ Rq, const float* __restrict__ Rk,
                 const float* __restrict__ gq, const float* __restrict__ bq,
                 const float* __restrict__ gk, const float* __restrict__ bk,
                 float* __restrict__ out)
{
  const int row = blockIdx.x;
  const u16 *X; const float *R, *G, *Bt; float* O;
  if (row < 4096) {
    X = TQ + (size_t)row * 1024; R = Rq + (size_t)row * 1024;
    G = gq; Bt = bq; O = out + (size_t)row * 1024;
  } else {
    const int r2 = row - 4096;
    X = TK + (size_t)r2 * 1024; R = Rk + (size_t)r2 * 1024;
    G = gk; Bt = bk; O = out + (size_t)4096 * 1024 + (size_t)r2 * 1024;
  }
  const int tid = threadIdx.x;
  float v[4], sum = 0.f, sumsq = 0.f;
#pragma unroll
  for (int i = 0; i < 4; ++i) {
    const int c = tid + i * 256;
    const float x = b2f(X[c]) + R[c];
    v[i] = x; sum += x; sumsq += x * x;
  }
#pragma unroll
  for (int sh = 1; sh < 64; sh <<= 1) {
    sum += __shfl_xor(sum, sh, 64);
    sumsq += __shfl_xor(sumsq, sh, 64);
  }
  __shared__ float sm[8];
  const int wave = tid >> 6, lane = tid & 63;
  if (lane == 0) { sm[wave] = sum; sm[4 + wave] = sumsq; }
  __syncthreads();
  sum = sm[0] + sm[1] + sm[2] + sm[3];
  sumsq = sm[4] + sm[5] + sm[6] + sm[7];
  const float mu = sum * (1.f / 1024.f);
  const float var = sumsq * (1.f / 1024.f) - mu * mu;
  const float rstd = rsqrtf(var + 1e-5f);
#pragma unroll
  for (int i = 0; i < 4; ++i) {
    const int c = tid + i * 256;
    O[c] = (v[i] - mu) * rstd * G[c] + Bt[c];   // f32 output per reference dtype
  }
}

extern "C" void kernel_launch(void* const* d_in, const int* in_sizes, int n_in,
                              void* d_out, int out_size, void* d_ws, size_t ws_size,
                              hipStream_t stream)
{
  // Inputs f32, output f32 (reference dtypes). Internals bf16 for MFMA.
  const float* query = (const float*)d_in[0];
  const float* key   = (const float*)d_in[1];
  const float* value = (const float*)d_in[2];
  const float* Wq  = (const float*)d_in[3];  const float* bq  = (const float*)d_in[4];
  const float* Wk  = (const float*)d_in[5];  const float* bk  = (const float*)d_in[6];
  const float* Wv  = (const float*)d_in[7];  const float* bv  = (const float*)d_in[8];
  const float* Wfq = (const float*)d_in[9];  const float* bfq = (const float*)d_in[10];
  const float* Wfk = (const float*)d_in[11]; const float* bfk = (const float*)d_in[12];
  const float* gq = (const float*)d_in[13];  const float* betaq = (const float*)d_in[14];
  const float* gk = (const float*)d_in[15];  const float* betak = (const float*)d_in[16];
  float* out = (float*)d_out;
  u16* ws  = (u16*)d_ws;

  const size_t SZ = (size_t)4096 * 1024;  // elements per [B*S, D] buffer
  u16* Qb = ws;            // projected Q (bf16)
  u16* Kb = ws + SZ;       // projected K
  u16* Vb = ws + 2 * SZ;   // projected V
  u16* XQ = (u16*)out;           // attention out (q) — bf16 scratch inside 32MB d_out
  u16* XK = (u16*)out + SZ;      // attention out (k)
  u16* TQ = Qb;            // proj outputs reuse dead Q/K buffers
  u16* TK = Kb;

  // 1) QKV projections (f32 A, f32 W -> bf16)
  gemm_nt_bias<1><<<dim3(32, 8, 3), 256, 0, stream>>>(query, Wq, bq, Qb,
                                                      key,   Wk, bk, Kb,
                                                      value, Wv, bv, Vb);
  // 2) Q->K attention, then K->Q attention (same kernel, pointers swapped, V shared)
  flash64<<<dim3(16, 64), 256, 0, stream>>>(Qb, Kb, Vb, XQ);
  flash64<<<dim3(16, 64), 256, 0, stream>>>(Kb, Qb, Vb, XK);
  // 3) output projections (bf16 A, f32 W -> bf16); reads d_out scratch, writes ws
  gemm_nt_bias<0><<<dim3(32, 8, 2), 256, 0, stream>>>(XQ, Wfq, bfq, TQ,
                                                      XK, Wfk, bfk, TK,
                                                      XK, Wfk, bfk, TK);
  // 4) residual + layernorm -> d_out as f32 (query_out | key_out), overwrites XQ/XK
  ln_residual<<<dim3(8192), 256, 0, stream>>>(TQ, TK, query, key,
                                              gq, betaq, gk, betak, out);
}

// Round 9
// 363.870 us; speedup vs baseline: 1.2803x; 1.2803x over previous
//
#include <hip/hip_runtime.h>

typedef unsigned short u16;
typedef unsigned int u32;
typedef __attribute__((ext_vector_type(8))) short short8;
typedef __attribute__((ext_vector_type(4))) float floatx4;

__device__ __forceinline__ float b2f(u16 v) {
  union { u32 u; float f; } x; x.u = ((u32)v) << 16; return x.f;
}
__device__ __forceinline__ u16 f2bf(float f) {
  union { float f; u32 u; } x; x.f = f;
  u32 r = (x.u + 0x7fffu + ((x.u >> 16) & 1u)) >> 16;  // RNE
  return (u16)r;
}
// XOR-swizzled LDS offset for a 64x64-u16 tile (row stride 128B = all 32 banks).
// Logical (row, col) -> physical; 16B chunk index xor'd with (row&7) so that
// l16-strided fragment reads become 2-way (free) instead of 16-way conflicts.
__device__ __forceinline__ int sw(int row, int col) {
  return row * 64 + ((((col >> 3) ^ row) & 7) << 3) + (col & 7);
}

// C(bf16) = A @ W^T + bias ; A:[4096,1024] (f32 or bf16), W:[1024,1024] f32 ([out,in]).
// 128x128 tile, BK=64, 4 waves 2x2, each wave 64x64 via 4x4 of 16x16x32 bf16 MFMA.
// TRANS2: z==2 writes C transposed ([1024][4096]) to feed flash's V^T B-operand.
template <int A_IS_F32, int TRANS2>
__global__ __launch_bounds__(256, 2)
void gemm_nt_bias(const void* __restrict__ A0, const float* __restrict__ W0, const float* __restrict__ B0, u16* __restrict__ C0,
                  const void* __restrict__ A1, const float* __restrict__ W1, const float* __restrict__ B1, u16* __restrict__ C1,
                  const void* __restrict__ A2, const float* __restrict__ W2, const float* __restrict__ B2, u16* __restrict__ C2)
{
  constexpr int K = 1024, N = 1024;
  __shared__ __attribute__((aligned(16))) u16 As[128 * 64];
  __shared__ __attribute__((aligned(16))) u16 Bs[128 * 64];

  const int z = blockIdx.z;
  const void*  A  = z == 0 ? A0 : (z == 1 ? A1 : A2);
  const float* W  = z == 0 ? W0 : (z == 1 ? W1 : W2);
  const float* Bi = z == 0 ? B0 : (z == 1 ? B1 : B2);
  u16*         C  = z == 0 ? C0 : (z == 1 ? C1 : C2);

  const int tid  = threadIdx.x;
  const int lane = tid & 63;
  const int wave = tid >> 6;
  const int l16  = lane & 15;
  const int quad = lane >> 4;
  const int wm = wave >> 1, wn = wave & 1;
  const int m0 = blockIdx.x * 128;
  const int n0 = blockIdx.y * 128;

  floatx4 acc[4][4];
#pragma unroll
  for (int i = 0; i < 4; ++i)
#pragma unroll
    for (int j = 0; j < 4; ++j)
#pragma unroll
      for (int e = 0; e < 4; ++e) acc[i][j][e] = 0.f;

  for (int k0 = 0; k0 < K; k0 += 64) {
#pragma unroll
    for (int i = 0; i < 4; ++i) {
      const int f = i * 256 + tid;
      const int r = f >> 3;            // row 0..127 (swizzle uses r&7)
      const int c = (f & 7) * 8;       // k-offset 0..56
      u16 ta[8];
      if (A_IS_F32) {
        const float* pa = (const float*)A + (size_t)(m0 + r) * K + k0 + c;
        float4 a0 = *(const float4*)pa, a1 = *(const float4*)(pa + 4);
        ta[0] = f2bf(a0.x); ta[1] = f2bf(a0.y); ta[2] = f2bf(a0.z); ta[3] = f2bf(a0.w);
        ta[4] = f2bf(a1.x); ta[5] = f2bf(a1.y); ta[6] = f2bf(a1.z); ta[7] = f2bf(a1.w);
      } else {
        const u16* pa = (const u16*)A + (size_t)(m0 + r) * K + k0 + c;
        *(uint4*)ta = *(const uint4*)pa;
      }
      *(uint4*)&As[sw(r, c)] = *(const uint4*)ta;
      const float* pw = W + (size_t)(n0 + r) * K + k0 + c;
      float4 w0 = *(const float4*)pw, w1 = *(const float4*)(pw + 4);
      u16 tw[8];
      tw[0] = f2bf(w0.x); tw[1] = f2bf(w0.y); tw[2] = f2bf(w0.z); tw[3] = f2bf(w0.w);
      tw[4] = f2bf(w1.x); tw[5] = f2bf(w1.y); tw[6] = f2bf(w1.z); tw[7] = f2bf(w1.w);
      *(uint4*)&Bs[sw(r, c)] = *(const uint4*)tw;
    }
    __syncthreads();
#pragma unroll
    for (int ks = 0; ks < 2; ++ks) {
      short8 af[4], bf[4];
#pragma unroll
      for (int mt = 0; mt < 4; ++mt)
        af[mt] = *(const short8*)&As[sw(wm * 64 + mt * 16 + l16, ks * 32 + quad * 8)];
#pragma unroll
      for (int nt = 0; nt < 4; ++nt)
        bf[nt] = *(const short8*)&Bs[sw(wn * 64 + nt * 16 + l16, ks * 32 + quad * 8)];
#pragma unroll
      for (int mt = 0; mt < 4; ++mt)
#pragma unroll
        for (int nt = 0; nt < 4; ++nt)
          acc[mt][nt] = __builtin_amdgcn_mfma_f32_16x16x32_bf16(af[mt], bf[nt], acc[mt][nt], 0, 0, 0);
    }
    __syncthreads();
  }

  float bb[4];
#pragma unroll
  for (int nt = 0; nt < 4; ++nt) bb[nt] = Bi[n0 + wn * 64 + nt * 16 + l16];

  if (TRANS2 && z == 2) {
    // C^T[col][row]: lane writes 4 consecutive tokens (8B) per (mt,nt)
#pragma unroll
    for (int mt = 0; mt < 4; ++mt) {
      const int rowb = m0 + wm * 64 + mt * 16 + quad * 4;
#pragma unroll
      for (int nt = 0; nt < 4; ++nt) {
        const int col = n0 + wn * 64 + nt * 16 + l16;
        u32 lo = (u32)f2bf(acc[mt][nt][0] + bb[nt]) | ((u32)f2bf(acc[mt][nt][1] + bb[nt]) << 16);
        u32 hi = (u32)f2bf(acc[mt][nt][2] + bb[nt]) | ((u32)f2bf(acc[mt][nt][3] + bb[nt]) << 16);
        uint2 w; w.x = lo; w.y = hi;
        *(uint2*)&C[(size_t)col * 4096 + rowb] = w;
      }
    }
  } else {
#pragma unroll
    for (int mt = 0; mt < 4; ++mt) {
#pragma unroll
      for (int r = 0; r < 4; ++r) {
        const int row = m0 + wm * 64 + mt * 16 + quad * 4 + r;
        u16* crow = C + (size_t)row * N + n0 + wn * 64 + l16;
#pragma unroll
        for (int nt = 0; nt < 4; ++nt)
          crow[nt * 16] = f2bf(acc[mt][nt][r] + bb[nt]);
      }
    }
  }
}

// Flash attention, Br=Bc=64, Hd=64. Q/K in [B*S,1024] (head cols h*64..+63),
// V pre-transposed: VT[1024][4096] (VT[h*64+d][b*1024+s]).
// Double-buffered K/V tiles (1 barrier/tile), ps overlays qs, all LDS swizzled.
__global__ __launch_bounds__(256, 4)
void flash64(const u16* __restrict__ Qw, const u16* __restrict__ Kw,
             const u16* __restrict__ VTw, u16* __restrict__ Ow)
{
  __shared__ __attribute__((aligned(16))) u16 ks[2][64 * 64];
  __shared__ __attribute__((aligned(16))) u16 vT[2][64 * 64];
  __shared__ __attribute__((aligned(16))) u16 qs[64 * 64];
  u16* ps = qs;  // qs dead after aq regs loaded

  const int tid  = threadIdx.x;
  const int lane = tid & 63;
  const int wave = tid >> 6;
  const int l16  = lane & 15;
  const int quad = lane >> 4;
  const int bh = blockIdx.y;
  const int b = bh >> 4, h = bh & 15;
  const int q0 = blockIdx.x * 64;
  const size_t colBase = (size_t)h * 64;
  const size_t qbase = ((size_t)(b * 1024 + q0)) * 1024 + colBase;

  // stage Q tile + first K/V tiles
  {
    const size_t kb = ((size_t)(b * 1024)) * 1024 + colBase;
    for (int i = tid; i < 512; i += 256) {
      const int r = i >> 3, c = (i & 7) * 8;
      *(uint4*)&qs[sw(r, c)] = *(const uint4*)&Qw[qbase + (size_t)r * 1024 + c];
      *(uint4*)&ks[0][sw(r, c)] = *(const uint4*)&Kw[kb + (size_t)r * 1024 + c];
      *(uint4*)&vT[0][sw(r, c)] = *(const uint4*)&VTw[(size_t)(h * 64 + r) * 4096 + b * 1024 + c];
    }
  }
  __syncthreads();
  short8 aq[2];
#pragma unroll
  for (int k2 = 0; k2 < 2; ++k2)
    aq[k2] = *(const short8*)&qs[sw(wave * 16 + l16, k2 * 32 + quad * 8)];

  floatx4 accO[4];
#pragma unroll
  for (int nt = 0; nt < 4; ++nt)
#pragma unroll
    for (int e = 0; e < 4; ++e) accO[nt][e] = 0.f;
  float mrow[4], lrow[4];
#pragma unroll
  for (int r = 0; r < 4; ++r) { mrow[r] = -1e30f; lrow[r] = 0.f; }

  for (int jt = 0; jt < 16; ++jt) {
    const int cur = jt & 1;
    __syncthreads();  // buf[cur] ready; all waves done with buf[1^cur] & qs(aq)

    if (jt + 1 < 16) {  // stage next tile into the other buffer
      const int nb = 1 ^ cur;
      const size_t kb = ((size_t)(b * 1024 + (jt + 1) * 64)) * 1024 + colBase;
      for (int i = tid; i < 512; i += 256) {
        const int r = i >> 3, c = (i & 7) * 8;
        *(uint4*)&ks[nb][sw(r, c)] = *(const uint4*)&Kw[kb + (size_t)r * 1024 + c];
        *(uint4*)&vT[nb][sw(r, c)] =
            *(const uint4*)&VTw[(size_t)(h * 64 + r) * 4096 + b * 1024 + (jt + 1) * 64 + c];
      }
    }

    floatx4 sacc[4];
#pragma unroll
    for (int nt = 0; nt < 4; ++nt)
#pragma unroll
      for (int e = 0; e < 4; ++e) sacc[nt][e] = 0.f;
#pragma unroll
    for (int k2 = 0; k2 < 2; ++k2) {
#pragma unroll
      for (int nt = 0; nt < 4; ++nt) {
        short8 bf = *(const short8*)&ks[cur][sw(nt * 16 + l16, k2 * 32 + quad * 8)];
        sacc[nt] = __builtin_amdgcn_mfma_f32_16x16x32_bf16(aq[k2], bf, sacc[nt], 0, 0, 0);
      }
    }

    const float scale = 0.125f;  // 1/sqrt(64)
    float mnew[4], alpha[4];
#pragma unroll
    for (int r = 0; r < 4; ++r) {
      float mx = fmaxf(fmaxf(sacc[0][r], sacc[1][r]), fmaxf(sacc[2][r], sacc[3][r])) * scale;
#pragma unroll
      for (int sh = 1; sh < 16; sh <<= 1) mx = fmaxf(mx, __shfl_xor(mx, sh, 64));
      mnew[r] = fmaxf(mrow[r], mx);
      alpha[r] = __expf(mrow[r] - mnew[r]);
      mrow[r] = mnew[r];
    }
#pragma unroll
    for (int nt = 0; nt < 4; ++nt) {
#pragma unroll
      for (int r = 0; r < 4; ++r) {
        float p = __expf(sacc[nt][r] * scale - mnew[r]);
        sacc[nt][r] = p;
        // C-layout -> A-layout via wave-private LDS strip (lgkmcnt orders w->r)
        ps[sw(wave * 16 + quad * 4 + r, nt * 16 + l16)] = f2bf(p);
      }
    }
#pragma unroll
    for (int r = 0; r < 4; ++r) {
      float s = sacc[0][r] + sacc[1][r] + sacc[2][r] + sacc[3][r];
#pragma unroll
      for (int sh = 1; sh < 16; sh <<= 1) s += __shfl_xor(s, sh, 64);
      lrow[r] = lrow[r] * alpha[r] + s;
#pragma unroll
      for (int nt = 0; nt < 4; ++nt) accO[nt][r] *= alpha[r];
    }
#pragma unroll
    for (int k2 = 0; k2 < 2; ++k2) {
      short8 ap = *(const short8*)&ps[sw(wave * 16 + l16, k2 * 32 + quad * 8)];
#pragma unroll
      for (int nt = 0; nt < 4; ++nt) {
        short8 bv = *(const short8*)&vT[cur][sw(nt * 16 + l16, k2 * 32 + quad * 8)];
        accO[nt] = __builtin_amdgcn_mfma_f32_16x16x32_bf16(ap, bv, accO[nt], 0, 0, 0);
      }
    }
  }

  const size_t obase = ((size_t)(b * 1024 + q0 + wave * 16 + quad * 4)) * 1024 + colBase;
#pragma unroll
  for (int nt = 0; nt < 4; ++nt)
#pragma unroll
    for (int r = 0; r < 4; ++r)
      Ow[obase + (size_t)r * 1024 + nt * 16 + l16] = f2bf(accO[nt][r] / lrow[r]);
}

// out(f32) = LN(residual_f32 + X_bf16) * gamma_f32 + beta_f32 ; one block per row of 1024
__global__ __launch_bounds__(256)
void ln_residual(const u16* __restrict__ TQ, const u16* __restrict__ TK,
                 const float* __restrict__ Rq, const float* __restrict__ Rk,
                 const float* __restrict__ gq, const float* __restrict__ bq,
                 const float* __restrict__ gk, const float* __restrict__ bk,
                 float* __restrict__ out)
{
  const int row = blockIdx.x;
  const u16 *X; const float *R, *G, *Bt; float* O;
  if (row < 4096) {
    X = TQ + (size_t)row * 1024; R = Rq + (size_t)row * 1024;
    G = gq; Bt = bq; O = out + (size_t)row * 1024;
  } else {
    const int r2 = row - 4096;
    X = TK + (size_t)r2 * 1024; R = Rk + (size_t)r2 * 1024;
    G = gk; Bt = bk; O = out + (size_t)4096 * 1024 + (size_t)r2 * 1024;
  }
  const int tid = threadIdx.x;
  float v[4], sum = 0.f, sumsq = 0.f;
#pragma unroll
  for (int i = 0; i < 4; ++i) {
    const int c = tid + i * 256;
    const float x = b2f(X[c]) + R[c];
    v[i] = x; sum += x; sumsq += x * x;
  }
#pragma unroll
  for (int sh = 1; sh < 64; sh <<= 1) {
    sum += __shfl_xor(sum, sh, 64);
    sumsq += __shfl_xor(sumsq, sh, 64);
  }
  __shared__ float sm[8];
  const int wave = tid >> 6, lane = tid & 63;
  if (lane == 0) { sm[wave] = sum; sm[4 + wave] = sumsq; }
  __syncthreads();
  sum = sm[0] + sm[1] + sm[2] + sm[3];
  sumsq = sm[4] + sm[5] + sm[6] + sm[7];
  const float mu = sum * (1.f / 1024.f);
  const float var = sumsq * (1.f / 1024.f) - mu * mu;
  const float rstd = rsqrtf(var + 1e-5f);
#pragma unroll
  for (int i = 0; i < 4; ++i) {
    const int c = tid + i * 256;
    O[c] = (v[i] - mu) * rstd * G[c] + Bt[c];
  }
}

extern "C" void kernel_launch(void* const* d_in, const int* in_sizes, int n_in,
                              void* d_out, int out_size, void* d_ws, size_t ws_size,
                              hipStream_t stream)
{
  // Inputs f32, output f32 (reference dtypes). Internals bf16 for MFMA.
  const float* query = (const float*)d_in[0];
  const float* key   = (const float*)d_in[1];
  const float* value = (const float*)d_in[2];
  const float* Wq  = (const float*)d_in[3];  const float* bq  = (const float*)d_in[4];
  const float* Wk  = (const float*)d_in[5];  const float* bk  = (const float*)d_in[6];
  const float* Wv  = (const float*)d_in[7];  const float* bv  = (const float*)d_in[8];
  const float* Wfq = (const float*)d_in[9];  const float* bfq = (const float*)d_in[10];
  const float* Wfk = (const float*)d_in[11]; const float* bfk = (const float*)d_in[12];
  const float* gq = (const float*)d_in[13];  const float* betaq = (const float*)d_in[14];
  const float* gk = (const float*)d_in[15];  const float* betak = (const float*)d_in[16];
  float* out = (float*)d_out;
  u16* ws  = (u16*)d_ws;

  const size_t SZ = (size_t)4096 * 1024;  // elements per [B*S, D] buffer
  u16* Qb = ws;            // projected Q (bf16)
  u16* Kb = ws + SZ;       // projected K
  u16* VT = ws + 2 * SZ;   // projected V, TRANSPOSED: [1024][4096]
  u16* XQ = (u16*)out;           // attention out (q) — bf16 scratch inside 32MB d_out
  u16* XK = (u16*)out + SZ;      // attention out (k)
  u16* TQ = Qb;            // proj outputs reuse dead Q/K buffers
  u16* TK = Kb;

  // 1) QKV projections (f32 A, f32 W -> bf16); z=2 (V) written transposed
  gemm_nt_bias<1, 1><<<dim3(32, 8, 3), 256, 0, stream>>>(query, Wq, bq, Qb,
                                                         key,   Wk, bk, Kb,
                                                         value, Wv, bv, VT);
  // 2) Q->K attention, then K->Q attention (same kernel, pointers swapped, V^T shared)
  flash64<<<dim3(16, 64), 256, 0, stream>>>(Qb, Kb, VT, XQ);
  flash64<<<dim3(16, 64), 256, 0, stream>>>(Kb, Qb, VT, XK);
  // 3) output projections (bf16 A, f32 W -> bf16); reads d_out scratch, writes ws
  gemm_nt_bias<0, 0><<<dim3(32, 8, 2), 256, 0, stream>>>(XQ, Wfq, bfq, TQ,
                                                         XK, Wfk, bfk, TK,
                                                         XK, Wfk, bfk, TK);
  // 4) residual + layernorm -> d_out as f32 (query_out | key_out), overwrites XQ/XK
  ln_residual<<<dim3(8192), 256, 0, stream>>>(TQ, TK, query, key,
                                              gq, betaq, gk, betak, out);
}

// Round 10
// 324.793 us; speedup vs baseline: 1.4343x; 1.1203x over previous
//
#include <hip/hip_runtime.h>

typedef unsigned short u16;
typedef unsigned int u32;
typedef __attribute__((ext_vector_type(8))) short short8;
typedef __attribute__((ext_vector_type(4))) float floatx4;

#define AS_GLOBAL __attribute__((address_space(1)))
#define AS_LDS    __attribute__((address_space(3)))

__device__ __forceinline__ float b2f(u16 v) {
  union { u32 u; float f; } x; x.u = ((u32)v) << 16; return x.f;
}
__device__ __forceinline__ u16 f2bf(float f) {
  union { float f; u32 u; } x; x.f = f;
  u32 r = (x.u + 0x7fffu + ((x.u >> 16) & 1u)) >> 16;  // RNE
  return (u16)r;
}
// async global->LDS, 16B/lane; LDS base wave-uniform, lane i -> base + i*16B
__device__ __forceinline__ void gl_lds16(const u16* g, u16* l) {
  __builtin_amdgcn_global_load_lds((const AS_GLOBAL u32*)g, (AS_LDS u32*)l, 16, 0, 0);
}
// XOR-swizzled LDS offset for 64x64-u16 tiles (flash kernel only).
__device__ __forceinline__ int sw(int row, int col) {
  return row * 64 + ((((col >> 3) ^ row) & 7) << 3) + (col & 7);
}

// f32 -> bf16 bulk convert; y selects tensor (0..2 big = nbig elems, 3..7 = nsmall).
__global__ __launch_bounds__(256)
void cvt8(const float* __restrict__ s0, const float* __restrict__ s1, const float* __restrict__ s2,
          const float* __restrict__ s3, const float* __restrict__ s4, const float* __restrict__ s5,
          const float* __restrict__ s6, const float* __restrict__ s7,
          u16* __restrict__ d0, u16* __restrict__ d1, u16* __restrict__ d2,
          u16* __restrict__ d3, u16* __restrict__ d4, u16* __restrict__ d5,
          u16* __restrict__ d6, u16* __restrict__ d7, int nbig, int nsmall)
{
  const int z = blockIdx.y;
  const float* s; u16* d; int n;
  switch (z) {
    case 0: s = s0; d = d0; n = nbig; break;
    case 1: s = s1; d = d1; n = nbig; break;
    case 2: s = s2; d = d2; n = nbig; break;
    case 3: s = s3; d = d3; n = nsmall; break;
    case 4: s = s4; d = d4; n = nsmall; break;
    case 5: s = s5; d = d5; n = nsmall; break;
    case 6: s = s6; d = d6; n = nsmall; break;
    default: s = s7; d = d7; n = nsmall; break;
  }
  const size_t idx = ((size_t)blockIdx.x * 256 + threadIdx.x) * 8;
  if (idx >= (size_t)n) return;
  float4 a0 = *(const float4*)(s + idx);
  float4 a1 = *(const float4*)(s + idx + 4);
  u16 t[8];
  t[0] = f2bf(a0.x); t[1] = f2bf(a0.y); t[2] = f2bf(a0.z); t[3] = f2bf(a0.w);
  t[4] = f2bf(a1.x); t[5] = f2bf(a1.y); t[6] = f2bf(a1.z); t[7] = f2bf(a1.w);
  *(uint4*)(d + idx) = *(const uint4*)t;
}

// C(bf16) = A @ W^T + bias(f32) ; A:[4096,1024] bf16, W:[1024,1024] bf16 ([out,in]).
// m97-form: 128x128 tile, BK=64, global_load_lds width-16 staging, 4 waves 2x2,
// each wave 64x64 via 4x4 of 16x16x32 bf16 MFMA.
// TRANS2: z==2 writes C transposed ([1024][4096]) to feed flash's V^T B-operand.
template <int TRANS2>
__global__ __launch_bounds__(256, 3)
void gemm_nt_bias(const u16* __restrict__ A0, const u16* __restrict__ W0, const float* __restrict__ B0, u16* __restrict__ C0,
                  const u16* __restrict__ A1, const u16* __restrict__ W1, const float* __restrict__ B1, u16* __restrict__ C1,
                  const u16* __restrict__ A2, const u16* __restrict__ W2, const float* __restrict__ B2, u16* __restrict__ C2)
{
  constexpr int K = 1024, N = 1024;
  __shared__ __attribute__((aligned(16))) u16 As[128 * 64];
  __shared__ __attribute__((aligned(16))) u16 Bs[128 * 64];

  const int z = blockIdx.z;
  const u16*   A  = z == 0 ? A0 : (z == 1 ? A1 : A2);
  const u16*   W  = z == 0 ? W0 : (z == 1 ? W1 : W2);
  const float* Bi = z == 0 ? B0 : (z == 1 ? B1 : B2);
  u16*         C  = z == 0 ? C0 : (z == 1 ? C1 : C2);

  const int tid  = threadIdx.x;
  const int lane = tid & 63;
  const int wave = tid >> 6;
  const int l16  = lane & 15;
  const int quad = lane >> 4;
  const int wm = wave >> 1, wn = wave & 1;
  const int m0 = blockIdx.x * 128;
  const int n0 = blockIdx.y * 128;

  floatx4 acc[4][4];
#pragma unroll
  for (int i = 0; i < 4; ++i)
#pragma unroll
    for (int j = 0; j < 4; ++j)
#pragma unroll
      for (int e = 0; e < 4; ++e) acc[i][j][e] = 0.f;

  // staging: per wave-instruction 8 rows x 64 k; 4 instrs/wave per matrix
  const int srow = wave * 32 + (lane >> 3);
  const int scol = (lane & 7) * 8;
  const u16* gA = A + (size_t)(m0 + srow) * K + scol;
  const u16* gW = W + (size_t)(n0 + srow) * K + scol;

  for (int k0 = 0; k0 < K; k0 += 64) {
#pragma unroll
    for (int i = 0; i < 4; ++i) {
      gl_lds16(gA + (size_t)(i * 8) * K + k0, &As[(wave * 32 + i * 8) * 64]);
      gl_lds16(gW + (size_t)(i * 8) * K + k0, &Bs[(wave * 32 + i * 8) * 64]);
    }
    __syncthreads();  // drains vmcnt for the async LDS loads
#pragma unroll
    for (int ks = 0; ks < 2; ++ks) {
      short8 af[4], bf[4];
#pragma unroll
      for (int mt = 0; mt < 4; ++mt)
        af[mt] = *(const short8*)&As[(wm * 64 + mt * 16 + l16) * 64 + ks * 32 + quad * 8];
#pragma unroll
      for (int nt = 0; nt < 4; ++nt)
        bf[nt] = *(const short8*)&Bs[(wn * 64 + nt * 16 + l16) * 64 + ks * 32 + quad * 8];
#pragma unroll
      for (int mt = 0; mt < 4; ++mt)
#pragma unroll
        for (int nt = 0; nt < 4; ++nt)
          acc[mt][nt] = __builtin_amdgcn_mfma_f32_16x16x32_bf16(af[mt], bf[nt], acc[mt][nt], 0, 0, 0);
    }
    __syncthreads();
  }

  float bb[4];
#pragma unroll
  for (int nt = 0; nt < 4; ++nt) bb[nt] = Bi[n0 + wn * 64 + nt * 16 + l16];

  if (TRANS2 && z == 2) {
    // C^T[col][row]: lane writes 4 consecutive tokens (8B) per (mt,nt)
#pragma unroll
    for (int mt = 0; mt < 4; ++mt) {
      const int rowb = m0 + wm * 64 + mt * 16 + quad * 4;
#pragma unroll
      for (int nt = 0; nt < 4; ++nt) {
        const int col = n0 + wn * 64 + nt * 16 + l16;
        u32 lo = (u32)f2bf(acc[mt][nt][0] + bb[nt]) | ((u32)f2bf(acc[mt][nt][1] + bb[nt]) << 16);
        u32 hi = (u32)f2bf(acc[mt][nt][2] + bb[nt]) | ((u32)f2bf(acc[mt][nt][3] + bb[nt]) << 16);
        uint2 w; w.x = lo; w.y = hi;
        *(uint2*)&C[(size_t)col * 4096 + rowb] = w;
      }
    }
  } else {
#pragma unroll
    for (int mt = 0; mt < 4; ++mt) {
#pragma unroll
      for (int r = 0; r < 4; ++r) {
        const int row = m0 + wm * 64 + mt * 16 + quad * 4 + r;
        u16* crow = C + (size_t)row * N + n0 + wn * 64 + l16;
#pragma unroll
        for (int nt = 0; nt < 4; ++nt)
          crow[nt * 16] = f2bf(acc[mt][nt][r] + bb[nt]);
      }
    }
  }
}

// Flash attention, Br=Bc=64, Hd=64. Q/K in [B*S,1024] (head cols h*64..+63),
// V pre-transposed: VT[1024][4096]. Double-buffered K/V tiles, ps overlays qs,
// all LDS XOR-swizzled. Swap (Q,K) for the K->Q branch (V shared).
__global__ __launch_bounds__(256, 4)
void flash64(const u16* __restrict__ Qw, const u16* __restrict__ Kw,
             const u16* __restrict__ VTw, u16* __restrict__ Ow)
{
  __shared__ __attribute__((aligned(16))) u16 ks[2][64 * 64];
  __shared__ __attribute__((aligned(16))) u16 vT[2][64 * 64];
  __shared__ __attribute__((aligned(16))) u16 qs[64 * 64];
  u16* ps = qs;  // qs dead after aq regs loaded

  const int tid  = threadIdx.x;
  const int lane = tid & 63;
  const int wave = tid >> 6;
  const int l16  = lane & 15;
  const int quad = lane >> 4;
  const int bh = blockIdx.y;
  const int b = bh >> 4, h = bh & 15;
  const int q0 = blockIdx.x * 64;
  const size_t colBase = (size_t)h * 64;
  const size_t qbase = ((size_t)(b * 1024 + q0)) * 1024 + colBase;

  {
    const size_t kb = ((size_t)(b * 1024)) * 1024 + colBase;
    for (int i = tid; i < 512; i += 256) {
      const int r = i >> 3, c = (i & 7) * 8;
      *(uint4*)&qs[sw(r, c)] = *(const uint4*)&Qw[qbase + (size_t)r * 1024 + c];
      *(uint4*)&ks[0][sw(r, c)] = *(const uint4*)&Kw[kb + (size_t)r * 1024 + c];
      *(uint4*)&vT[0][sw(r, c)] = *(const uint4*)&VTw[(size_t)(h * 64 + r) * 4096 + b * 1024 + c];
    }
  }
  __syncthreads();
  short8 aq[2];
#pragma unroll
  for (int k2 = 0; k2 < 2; ++k2)
    aq[k2] = *(const short8*)&qs[sw(wave * 16 + l16, k2 * 32 + quad * 8)];

  floatx4 accO[4];
#pragma unroll
  for (int nt = 0; nt < 4; ++nt)
#pragma unroll
    for (int e = 0; e < 4; ++e) accO[nt][e] = 0.f;
  float mrow[4], lrow[4];
#pragma unroll
  for (int r = 0; r < 4; ++r) { mrow[r] = -1e30f; lrow[r] = 0.f; }

  for (int jt = 0; jt < 16; ++jt) {
    const int cur = jt & 1;
    __syncthreads();

    if (jt + 1 < 16) {
      const int nb = 1 ^ cur;
      const size_t kb = ((size_t)(b * 1024 + (jt + 1) * 64)) * 1024 + colBase;
      for (int i = tid; i < 512; i += 256) {
        const int r = i >> 3, c = (i & 7) * 8;
        *(uint4*)&ks[nb][sw(r, c)] = *(const uint4*)&Kw[kb + (size_t)r * 1024 + c];
        *(uint4*)&vT[nb][sw(r, c)] =
            *(const uint4*)&VTw[(size_t)(h * 64 + r) * 4096 + b * 1024 + (jt + 1) * 64 + c];
      }
    }

    floatx4 sacc[4];
#pragma unroll
    for (int nt = 0; nt < 4; ++nt)
#pragma unroll
      for (int e = 0; e < 4; ++e) sacc[nt][e] = 0.f;
#pragma unroll
    for (int k2 = 0; k2 < 2; ++k2) {
#pragma unroll
      for (int nt = 0; nt < 4; ++nt) {
        short8 bf = *(const short8*)&ks[cur][sw(nt * 16 + l16, k2 * 32 + quad * 8)];
        sacc[nt] = __builtin_amdgcn_mfma_f32_16x16x32_bf16(aq[k2], bf, sacc[nt], 0, 0, 0);
      }
    }

    const float scale = 0.125f;  // 1/sqrt(64)
    float mnew[4], alpha[4];
#pragma unroll
    for (int r = 0; r < 4; ++r) {
      float mx = fmaxf(fmaxf(sacc[0][r], sacc[1][r]), fmaxf(sacc[2][r], sacc[3][r])) * scale;
#pragma unroll
      for (int sh = 1; sh < 16; sh <<= 1) mx = fmaxf(mx, __shfl_xor(mx, sh, 64));
      mnew[r] = fmaxf(mrow[r], mx);
      alpha[r] = __expf(mrow[r] - mnew[r]);
      mrow[r] = mnew[r];
    }
#pragma unroll
    for (int nt = 0; nt < 4; ++nt) {
#pragma unroll
      for (int r = 0; r < 4; ++r) {
        float p = __expf(sacc[nt][r] * scale - mnew[r]);
        sacc[nt][r] = p;
        ps[sw(wave * 16 + quad * 4 + r, nt * 16 + l16)] = f2bf(p);
      }
    }
#pragma unroll
    for (int r = 0; r < 4; ++r) {
      float s = sacc[0][r] + sacc[1][r] + sacc[2][r] + sacc[3][r];
#pragma unroll
      for (int sh = 1; sh < 16; sh <<= 1) s += __shfl_xor(s, sh, 64);
      lrow[r] = lrow[r] * alpha[r] + s;
#pragma unroll
      for (int nt = 0; nt < 4; ++nt) accO[nt][r] *= alpha[r];
    }
#pragma unroll
    for (int k2 = 0; k2 < 2; ++k2) {
      short8 ap = *(const short8*)&ps[sw(wave * 16 + l16, k2 * 32 + quad * 8)];
#pragma unroll
      for (int nt = 0; nt < 4; ++nt) {
        short8 bv = *(const short8*)&vT[cur][sw(nt * 16 + l16, k2 * 32 + quad * 8)];
        accO[nt] = __builtin_amdgcn_mfma_f32_16x16x32_bf16(ap, bv, accO[nt], 0, 0, 0);
      }
    }
  }

  const size_t obase = ((size_t)(b * 1024 + q0 + wave * 16 + quad * 4)) * 1024 + colBase;
#pragma unroll
  for (int nt = 0; nt < 4; ++nt)
#pragma unroll
    for (int r = 0; r < 4; ++r)
      Ow[obase + (size_t)r * 1024 + nt * 16 + l16] = f2bf(accO[nt][r] / lrow[r]);
}

// out(f32) = LN(residual_f32 + X_bf16) * gamma_f32 + beta_f32 ; one block per row of 1024
__global__ __launch_bounds__(256)
void ln_residual(const u16* __restrict__ TQ, const u16* __restrict__ TK,
                 const float* __restrict__ Rq, const float* __restrict__ Rk,
                 const float* __restrict__ gq, const float* __restrict__ bq,
                 const float* __restrict__ gk, const float* __restrict__ bk,
                 float* __restrict__ out)
{
  const int row = blockIdx.x;
  const u16 *X; const float *R, *G, *Bt; float* O;
  if (row < 4096) {
    X = TQ + (size_t)row * 1024; R = Rq + (size_t)row * 1024;
    G = gq; Bt = bq; O = out + (size_t)row * 1024;
  } else {
    const int r2 = row - 4096;
    X = TK + (size_t)r2 * 1024; R = Rk + (size_t)r2 * 1024;
    G = gk; Bt = bk; O = out + (size_t)4096 * 1024 + (size_t)r2 * 1024;
  }
  const int tid = threadIdx.x;
  float v[4], sum = 0.f, sumsq = 0.f;
#pragma unroll
  for (int i = 0; i < 4; ++i) {
    const int c = tid + i * 256;
    const float x = b2f(X[c]) + R[c];
    v[i] = x; sum += x; sumsq += x * x;
  }
#pragma unroll
  for (int sh = 1; sh < 64; sh <<= 1) {
    sum += __shfl_xor(sum, sh, 64);
    sumsq += __shfl_xor(sumsq, sh, 64);
  }
  __shared__ float sm[8];
  const int wave = tid >> 6, lane = tid & 63;
  if (lane == 0) { sm[wave] = sum; sm[4 + wave] = sumsq; }
  __syncthreads();
  sum = sm[0] + sm[1] + sm[2] + sm[3];
  sumsq = sm[4] + sm[5] + sm[6] + sm[7];
  const float mu = sum * (1.f / 1024.f);
  const float var = sumsq * (1.f / 1024.f) - mu * mu;
  const float rstd = rsqrtf(var + 1e-5f);
#pragma unroll
  for (int i = 0; i < 4; ++i) {
    const int c = tid + i * 256;
    O[c] = (v[i] - mu) * rstd * G[c] + Bt[c];
  }
}

extern "C" void kernel_launch(void* const* d_in, const int* in_sizes, int n_in,
                              void* d_out, int out_size, void* d_ws, size_t ws_size,
                              hipStream_t stream)
{
  // Inputs f32, output f32. One bulk cvt pass -> all-bf16 m97-style GEMMs.
  const float* query = (const float*)d_in[0];
  const float* key   = (const float*)d_in[1];
  const float* value = (const float*)d_in[2];
  const float* Wq  = (const float*)d_in[3];  const float* bq  = (const float*)d_in[4];
  const float* Wk  = (const float*)d_in[5];  const float* bk  = (const float*)d_in[6];
  const float* Wv  = (const float*)d_in[7];  const float* bv  = (const float*)d_in[8];
  const float* Wfq = (const float*)d_in[9];  const float* bfq = (const float*)d_in[10];
  const float* Wfk = (const float*)d_in[11]; const float* bfk = (const float*)d_in[12];
  const float* gq = (const float*)d_in[13];  const float* betaq = (const float*)d_in[14];
  const float* gk = (const float*)d_in[15];  const float* betak = (const float*)d_in[16];
  float* out = (float*)d_out;
  u16* ws  = (u16*)d_ws;

  const size_t SZ = (size_t)4096 * 1024;  // 4M elems per [B*S, D] tensor
  const size_t WZ = (size_t)1024 * 1024;  // 1M elems per weight
  // ws (34 MB): Qb | Kb | VT | 5 bf16 weights
  u16* Qb  = ws;
  u16* Kb  = ws + SZ;
  u16* VT  = ws + 2 * SZ;           // projected V, TRANSPOSED [1024][4096]
  u16* Wqb = ws + 3 * SZ;
  u16* Wkb = Wqb + WZ;
  u16* Wvb = Wkb + WZ;
  u16* Wfqb = Wvb + WZ;
  u16* Wfkb = Wfqb + WZ;
  // d_out (32 MB) as staged scratch: qbf/kbf/vbf (24 MB) die after GEMM1;
  // XQ/XK (16 MB) die after GEMM2; final LN overwrites everything with f32.
  u16* qbf = (u16*)out;
  u16* kbf = qbf + SZ;
  u16* vbf = kbf + SZ;
  u16* XQ = (u16*)out;
  u16* XK = (u16*)out + SZ;
  u16* TQ = Qb;                     // proj outputs reuse dead Q/K buffers
  u16* TK = Kb;

  // 0) bulk f32->bf16 conversion (3 big + 5 weights)
  cvt8<<<dim3(2048, 8), 256, 0, stream>>>(query, key, value, Wq, Wk, Wv, Wfq, Wfk,
                                          qbf, kbf, vbf, Wqb, Wkb, Wvb, Wfqb, Wfkb,
                                          (int)SZ, (int)WZ);
  // 1) QKV projections (bf16 x bf16 -> bf16); z=2 (V) written transposed
  gemm_nt_bias<1><<<dim3(32, 8, 3), 256, 0, stream>>>(qbf, Wqb, bq, Qb,
                                                      kbf, Wkb, bk, Kb,
                                                      vbf, Wvb, bv, VT);
  // 2) Q->K attention, then K->Q attention (pointers swapped, V^T shared)
  flash64<<<dim3(16, 64), 256, 0, stream>>>(Qb, Kb, VT, XQ);
  flash64<<<dim3(16, 64), 256, 0, stream>>>(Kb, Qb, VT, XK);
  // 3) output projections; reads d_out scratch, writes ws
  gemm_nt_bias<0><<<dim3(32, 8, 2), 256, 0, stream>>>(XQ, Wfqb, bfq, TQ,
                                                      XK, Wfkb, bfk, TK,
                                                      XK, Wfkb, bfk, TK);
  // 4) residual + layernorm -> d_out as f32 (query_out | key_out)
  ln_residual<<<dim3(8192), 256, 0, stream>>>(TQ, TK, query, key,
                                              gq, betaq, gk, betak, out);
}